// Round 8
// baseline (215.223 us; speedup 1.0000x reference)
//
#include <hip/hip_runtime.h>
#include <math.h>

#define SEQ 512
#define HID 768
#define NBATCH 16
#define ROWS 8192
#define INV_SQRT_D 0.07216878364870323f

typedef short s8v __attribute__((ext_vector_type(8)));
typedef _Float16 h8v __attribute__((ext_vector_type(8)));
typedef float f4v __attribute__((ext_vector_type(4)));
typedef unsigned short u16;

// ---- fp16 helper (RNE) ----
__device__ __forceinline__ u16 f2h(float f) {
  _Float16 h = (_Float16)f;
  return __builtin_bit_cast(u16, h);
}

// ---- async global->LDS 16B copy (m97/m151: 1.35x over reg-staging) ----
// LDS dest must be wave-uniform base (HW adds lane*16); global src is per-lane.
__device__ __forceinline__ void llds16(const u16* g, u16* l) {
  __builtin_amdgcn_global_load_lds(
      (const __attribute__((address_space(1))) void*)g,
      (__attribute__((address_space(3))) void*)l, 16, 0, 0);
}

// ---------------------------------------------------------------------------
// fp16 GEMM core v3 (R18): counted-vmcnt 2-deep pipeline (T4 proper).
// R7's lesson (and m218's): a 2-phase split whose barrier still drains
// vmcnt(0) is no better than 1-phase. Here NO vmcnt(0) in steady state:
//   prologue: stage tile0->buf0, tile1->buf1 (8 loads in flight)
//   iter ks : s_waitcnt vmcnt(4)   // oldest stage (ks) retired; 4 newer fly
//             s_barrier            // raw: all waves' stage(ks) visible
//             sched_barrier(0)     // fence: no ds_read hoists above
//             16 MFMA on buf[ks&1]
//             s_barrier            // raw: all waves done reading buf[ks&1]
//             sched_barrier(0)     // fence: no stage hoists above
//             stage tile(ks+2) -> buf[ks&1]
// WAR safe: ds_reads complete before their consuming MFMAs issue, which
// precede the barrier. Extra compiler-hoisted vmem ops only make vmcnt(4)
// over-wait (safe). LDS stays 32KB (4 blocks/CU). csw source pre-swizzle
// (m173) + fo2 read swizzle: conflict-free b128.
// ---------------------------------------------------------------------------
template <int KSTEPS>   // number of 32-wide steps; >= 2
__device__ __forceinline__ void mm_core128(
    const u16* __restrict__ A, const int lda,
    const u16* __restrict__ B, const int ldb,
    u16* lds, f4v (&acc)[4][4])
{
  const int tid = threadIdx.x;
  const int w = tid >> 6, ln = tid & 63;
  const u16* src = (w >> 1) ? B : A;
  const int ld = (w >> 1) ? ldb : lda;
  const int half = w & 1;
  const int srow = ln >> 2;
  const int csw  = ((ln & 3) - (ln >> 3)) & 3;
  const int ml = ln & 15;
  const int fo2 = (((ln >> 4) + ((ln >> 1) & 3)) & 3) * 8;
  const int wr = (w >> 1) * 64, wc = (w & 1) * 64;

  const u16* gp[4];
  u16* lp[4];
#pragma unroll
  for (int t = 0; t < 4; ++t) {
    const int row = half * 64 + t * 16 + srow;
    gp[t] = src + (size_t)row * ld + csw * 8;
    lp[t] = lds + (w >> 1) * 4096 + half * 2048 + t * 512;   // wave-uniform
  }

  // prologue: stage tiles 0 and 1
#pragma unroll
  for (int t = 0; t < 4; ++t) llds16(gp[t], lp[t]);
#pragma unroll
  for (int t = 0; t < 4; ++t) llds16(gp[t] + 32, lp[t] + 8192);

#pragma unroll
  for (int ks = 0; ks < KSTEPS; ++ks) {
    if (ks < KSTEPS - 1) {
      asm volatile("s_waitcnt vmcnt(4)" ::: "memory");
    } else {
      asm volatile("s_waitcnt vmcnt(0)" ::: "memory");
    }
    __builtin_amdgcn_s_barrier();
    __builtin_amdgcn_sched_barrier(0);
    const int so = (ks & 1) * 8192;
    h8v a[4], b[4];
#pragma unroll
    for (int i = 0; i < 4; ++i)
      a[i] = *(const h8v*)&lds[so + (wr + i * 16 + ml) * 32 + fo2];
#pragma unroll
    for (int j = 0; j < 4; ++j)
      b[j] = *(const h8v*)&lds[so + 4096 + (wc + j * 16 + ml) * 32 + fo2];
#pragma unroll
    for (int i = 0; i < 4; ++i)
#pragma unroll
      for (int j = 0; j < 4; ++j)
        acc[i][j] = __builtin_amdgcn_mfma_f32_16x16x32_f16(a[i], b[j], acc[i][j], 0, 0, 0);
    __builtin_amdgcn_s_barrier();
    __builtin_amdgcn_sched_barrier(0);
    if (ks + 2 < KSTEPS) {
      const int k0 = (ks + 2) * 32;
#pragma unroll
      for (int t = 0; t < 4; ++t) llds16(gp[t] + k0, lp[t] + so);
    }
  }
}

// ---- prep: x -> fp16 ----
__global__ __launch_bounds__(256) void splitx(const float* __restrict__ x,
                                              u16* __restrict__ xh)
{
  const int i = blockIdx.x * 256 + threadIdx.x;
  const float4 v = ((const float4*)x)[i];
  ((ushort4*)xh)[i] = make_ushort4(f2h(v.x), f2h(v.y), f2h(v.z), f2h(v.w));
}

// ---- prep: transpose weights: WT[z][n][k] = W_z[k][n], fp16 ----
__global__ __launch_bounds__(256) void wsplit(
    const float* __restrict__ Wq, const float* __restrict__ Wk,
    const float* __restrict__ Wv, const float* __restrict__ Wo,
    u16* __restrict__ WTh)
{
  __shared__ float t[32][33];
  const int z = blockIdx.z;
  const float* W = (z == 0) ? Wq : (z == 1) ? Wk : (z == 2) ? Wv : Wo;
  const int n0 = blockIdx.x * 32, k0 = blockIdx.y * 32;
  const int tx = threadIdx.x & 31, ty = threadIdx.x >> 5;
#pragma unroll
  for (int i = 0; i < 4; ++i)
    t[ty + 8 * i][tx] = W[(size_t)(k0 + ty + 8 * i) * HID + n0 + tx];
  __syncthreads();
#pragma unroll
  for (int i = 0; i < 4; ++i) {
    const float v = t[tx][ty + 8 * i];
    const size_t idx = (size_t)z * HID * HID + (size_t)(n0 + ty + 8 * i) * HID + k0 + tx;
    WTh[idx] = f2h(v);
  }
}

// ---- QKV GEMM, XCD-swizzled 1D grid (1152 blocks), counted-vmcnt gll core.
//      All epilogues go through LDS for coalesced 16B stores. ----
__global__ __launch_bounds__(256, 4) void qkv_mm(
    const u16* __restrict__ xh, const u16* __restrict__ WTh,
    const float* __restrict__ bq, const float* __restrict__ bk, const float* __restrict__ bv,
    u16* __restrict__ qh, u16* __restrict__ kh, u16* __restrict__ vTh)
{
  __shared__ u16 lds[18432];        // mm_core: 16384; epilogue: 128x144 max
  const int id = blockIdx.x;
  const int xcd = id & 7;
  const int s = id >> 3;            // 0..143
  const int bx = s % 6;
  const int yl = (s / 6) & 7;
  const int z  = s / 48;
  const int bm = (yl * 8 + xcd) * 128;
  const int bn = bx * 128;
  const size_t wtoff = (size_t)z * HID * HID + (size_t)bn * HID;
  f4v acc[4][4];
#pragma unroll
  for (int i = 0; i < 4; ++i)
#pragma unroll
    for (int j = 0; j < 4; ++j) acc[i][j] = (f4v)0.f;
  mm_core128<24>(xh + (size_t)bm * HID, HID, WTh + wtoff, HID, lds, acc);
  const int tid = threadIdx.x, w = tid >> 6, ln = tid & 63;
  const int ml = ln & 15, quad = ln >> 4;
  const int wr = (w >> 1) * 64, wc = (w & 1) * 64;
  if (z == 2) {
    // transpose via LDS: lds[n_local*136 + seq_local], then coalesced out
    __syncthreads();                       // mm_core's last LDS reads done
#pragma unroll
    for (int i = 0; i < 4; ++i)
#pragma unroll
      for (int j = 0; j < 4; ++j) {
        const int ncol = wc + j * 16 + ml;
        const float bv_ = bv[bn + ncol];
#pragma unroll
        for (int r = 0; r < 4; ++r) {
          const int srow = wr + i * 16 + quad * 4 + r;
          lds[ncol * 136 + srow] = f2h(acc[i][j][r] + bv_);
        }
      }
    __syncthreads();
    u16* vb = vTh + (size_t)(bm >> 9) * HID * SEQ;
    const int sq0 = bm & 511;
    const int c8 = (tid & 15) * 8;
#pragma unroll
    for (int p = 0; p < 8; ++p) {
      const int nl = p * 16 + (tid >> 4);  // 0..127
      const s8v val = *(const s8v*)&lds[nl * 136 + c8];
      *(s8v*)&vb[(size_t)(bn + nl) * SEQ + sq0 + c8] = val;
    }
  } else {
    // q/k: row-major LDS tile (stride 132), then 16B coalesced row stores
    const float* bias = (z == 0) ? bq : bk;
    u16* dst = (z == 0) ? qh : kh;
    __syncthreads();                       // mm_core's last LDS reads done
#pragma unroll
    for (int i = 0; i < 4; ++i)
#pragma unroll
      for (int j = 0; j < 4; ++j) {
        const int col = wc + j * 16 + ml;
        const float bv_ = bias[bn + col];
#pragma unroll
        for (int r = 0; r < 4; ++r) {
          const int row = wr + i * 16 + quad * 4 + r;
          lds[row * 132 + col] = f2h(acc[i][j][r] + bv_);
        }
      }
    __syncthreads();
    const int c8 = (tid & 15) * 8;
#pragma unroll
    for (int p = 0; p < 8; ++p) {
      const int rl = p * 16 + (tid >> 4);  // 0..127
      const s8v val = *(const s8v*)&lds[rl * 132 + c8];
      *(s8v*)&dst[(size_t)(bm + rl) * HID + bn + c8] = val;
    }
  }
}

// ---------------------------------------------------------------------------
// FLASH attention v5 (R16): 64 Q-rows/block, 512 blocks = 2 blocks/CU, one
// resident round. K/V staging via global_load_lds direct (m97 schedule):
// K = 6 sub-tiles [64][32], V = 2 sub-tiles [192][32], csw/fo2 swizzle on the
// per-lane GLOBAL source (m173), LDS dest linear-in-lane. QK^T 24 MFMA/wave
// -> max-free exp via g-table (exact; validated R11+) -> P[64][72] -> PV
// 24 MFMA/wave. Grid XCD-bijective: 8 (b,h)/XCD -> K+V 3.1MB < 4MB L2.
// LDS: K@0 (12288), V@12288 (12288), P@24576 (4608) u16 = 57KB +gtab+red.
// ---------------------------------------------------------------------------
__global__ __launch_bounds__(256, 2) void attn_fused(
    const u16* __restrict__ qh, const u16* __restrict__ kh,
    const u16* __restrict__ vTh, u16* __restrict__ ch)
{
  __shared__ u16 lds[29184];
  __shared__ float gtab[1024];
  __shared__ float red[4][32];
  const int f = blockIdx.x;            // 512 blocks
  const int xcd = f & 7, s = f >> 3;   // s: 0..63
  const int z = xcd * 8 + (s >> 3);    // (b,h) 0..63, 8 per XCD
  const int bm = (s & 7) * 64;
  const int b = z >> 2, hh = z & 3;
  const int tid = threadIdx.x, w = tid >> 6, ln = tid & 63;
  const int ml = ln & 15, quad = ln >> 4;
  const int rh = w >> 1, ch2 = w & 1;  // row-half / col-half of the wave
  const int fo2 = ((quad + ((ml >> 1) & 3)) & 3) * 8;

  // g-table: idx = (srow - scol) + 511
  for (int t = tid; t < 1023; t += 256) {
    const float fd = fabsf((float)(t - 511));
    gtab[t] = INV_SQRT_D * __expf(-0.1f * fminf(fd, 5.0f)) - 0.1f * fd;
  }

  const u16* qbase = qh + (size_t)(b * SEQ + bm + rh * 32) * HID + hh * 192;
  const u16* kbase = kh + (size_t)b * SEQ * HID + hh * 192;
  const u16* vbase = vTh + (size_t)b * HID * SEQ + (size_t)(hh * 192) * SEQ;

  // Q fragments in registers (wave's 32 rows)
  h8v qf[2][6];
#pragma unroll
  for (int i = 0; i < 2; ++i)
#pragma unroll
    for (int ks = 0; ks < 6; ++ks)
      qf[i][ks] = *(const h8v*)(qbase + (size_t)(i * 16 + ml) * HID + ks * 32 + quad * 8);

  // gll staging geometry: lane ln covers row (ln>>2), slot (ln&3); the
  // conflict-free swizzle is applied on the SOURCE chunk index (csw).
  const int srow16 = ln >> 2;
  const int csw = ((ln & 3) - (ln >> 3)) & 3;
  const u16* ksrc = kbase + (size_t)(w * 16 + srow16) * HID + csw * 8;
  const u16* vsrc = vbase + (size_t)(w * 48 + srow16) * SEQ + csw * 8;

  f4v acc2[2][6];
#pragma unroll
  for (int i = 0; i < 2; ++i)
#pragma unroll
    for (int jj = 0; jj < 6; ++jj) acc2[i][jj] = (f4v)0.f;
  float rsum[2][4];
#pragma unroll
  for (int i = 0; i < 2; ++i)
#pragma unroll
    for (int r = 0; r < 4; ++r) rsum[i][r] = 0.f;

  for (int j = 0; j < 8; ++j) {
    __syncthreads();                       // b1: prev-iter LDS reads done
    // ---- stage K_j (6 sub-tiles [64][32]) + V_j (2 sub-tiles [192][32]) ----
#pragma unroll
    for (int st = 0; st < 6; ++st)
      llds16(ksrc + (size_t)(j * 64) * HID + st * 32, lds + st * 2048 + w * 512);
#pragma unroll
    for (int st = 0; st < 2; ++st)
#pragma unroll
      for (int o = 0; o < 3; ++o)
        llds16(vsrc + (size_t)(o * 16) * SEQ + j * 64 + st * 32,
               lds + 12288 + st * 6144 + w * 1536 + o * 512);
    __syncthreads();                       // b2: vmcnt(0) drain + visibility
    // ---- QK^T: 24 MFMA/wave (64Q x 32K per wave) ----
    f4v sacc[2][2];
    sacc[0][0] = (f4v)0.f; sacc[0][1] = (f4v)0.f;
    sacc[1][0] = (f4v)0.f; sacc[1][1] = (f4v)0.f;
    __builtin_amdgcn_s_setprio(1);
#pragma unroll
    for (int ks = 0; ks < 6; ++ks) {
      h8v kf0 = *(const h8v*)&lds[ks * 2048 + (ch2 * 32 + ml) * 32 + fo2];
      h8v kf1 = *(const h8v*)&lds[ks * 2048 + (ch2 * 32 + 16 + ml) * 32 + fo2];
      sacc[0][0] = __builtin_amdgcn_mfma_f32_16x16x32_f16(qf[0][ks], kf0, sacc[0][0], 0, 0, 0);
      sacc[1][0] = __builtin_amdgcn_mfma_f32_16x16x32_f16(qf[1][ks], kf0, sacc[1][0], 0, 0, 0);
      sacc[0][1] = __builtin_amdgcn_mfma_f32_16x16x32_f16(qf[0][ks], kf1, sacc[0][1], 0, 0, 0);
      sacc[1][1] = __builtin_amdgcn_mfma_f32_16x16x32_f16(qf[1][ks], kf1, sacc[1][1], 0, 0, 0);
    }
    __builtin_amdgcn_s_setprio(0);
    // ---- transform + P write (max-free exp; 1 exp/elem via g-table) ----
#pragma unroll
    for (int i = 0; i < 2; ++i)
#pragma unroll
      for (int j2 = 0; j2 < 2; ++j2) {
        const int lcol = ch2 * 32 + j2 * 16 + ml;
        const int scolg = j * 64 + lcol;
#pragma unroll
        for (int r = 0; r < 4; ++r) {
          const int lrow = rh * 32 + i * 16 + quad * 4 + r;
          const float g = gtab[bm + lrow - scolg + 511];
          const float p = __expf(fmaf(sacc[i][j2][r], INV_SQRT_D, g));
          rsum[i][r] += p;
          lds[24576 + lrow * 72 + lcol] = f2h(p);
        }
      }
    __syncthreads();                       // b3: P_j visible
    // ---- PV: 24 MFMA/wave (64Q x 96 head-dims per wave) ----
    __builtin_amdgcn_s_setprio(1);
#pragma unroll
    for (int ks = 0; ks < 2; ++ks) {
      h8v pf[2], vf[6];
#pragma unroll
      for (int i = 0; i < 2; ++i)
        pf[i] = *(const h8v*)&lds[24576 + (rh * 32 + i * 16 + ml) * 72 + ks * 32 + quad * 8];
#pragma unroll
      for (int jj = 0; jj < 6; ++jj)
        vf[jj] = *(const h8v*)&lds[12288 + ks * 6144 + (ch2 * 96 + jj * 16 + ml) * 32 + fo2];
#pragma unroll
      for (int i = 0; i < 2; ++i)
#pragma unroll
        for (int jj = 0; jj < 6; ++jj)
          acc2[i][jj] = __builtin_amdgcn_mfma_f32_16x16x32_f16(pf[i], vf[jj], acc2[i][jj], 0, 0, 0);
    }
    __builtin_amdgcn_s_setprio(0);
  }

  // ---- final row-sum reduce ----
#pragma unroll
  for (int i = 0; i < 2; ++i)
#pragma unroll
    for (int r = 0; r < 4; ++r) {
      float t = rsum[i][r];
#pragma unroll
      for (int o = 1; o < 16; o <<= 1) t += __shfl_xor(t, o, 64);
      rsum[i][r] = t;
    }
  if (ml == 0) {
#pragma unroll
    for (int i = 0; i < 2; ++i)
#pragma unroll
      for (int r = 0; r < 4; ++r) red[w][i * 16 + quad * 4 + r] = rsum[i][r];
  }
  __syncthreads();

  // ---- ctx out (normalize here) ----
#pragma unroll
  for (int i = 0; i < 2; ++i)
#pragma unroll
    for (int r = 0; r < 4; ++r) {
      const int lr = i * 16 + quad * 4 + r;
      const float is = 1.0f / (red[rh * 2][lr] + red[rh * 2 + 1][lr]);
      const int m = bm + rh * 32 + lr;
#pragma unroll
      for (int jj = 0; jj < 6; ++jj) {
        const int gcol = hh * 192 + ch2 * 96 + jj * 16 + ml;
        ch[(size_t)(b * SEQ + m) * HID + gcol] = f2h(acc2[i][jj][r] * is);
      }
    }
}

// ---- projection GEMM + bias + residual -> h fp32 (XCD-swizzled, gll) ----
__global__ __launch_bounds__(256, 4) void proj_mm(
    const u16* __restrict__ ch, const u16* __restrict__ WTh,
    const float* __restrict__ bo, const float* __restrict__ x, float* __restrict__ h)
{
  __shared__ u16 lds[16384];
  const int id = blockIdx.x;
  const int xcd = id & 7;
  const int s = id >> 3;            // 0..47
  const int bx = s % 6;
  const int yl = s / 6;             // 0..7
  const int bm = (yl * 8 + xcd) * 128;
  const int bn = bx * 128;
  const size_t wtoff = (size_t)3 * HID * HID + (size_t)bn * HID;
  f4v acc[4][4];
#pragma unroll
  for (int i = 0; i < 4; ++i)
#pragma unroll
    for (int j = 0; j < 4; ++j) acc[i][j] = (f4v)0.f;
  mm_core128<24>(ch + (size_t)bm * HID, HID, WTh + wtoff, HID, lds, acc);
  const int tid = threadIdx.x, w = tid >> 6, ln = tid & 63;
  const int ml = ln & 15, quad = ln >> 4;
  const int wr = (w >> 1) * 64, wc = (w & 1) * 64;
#pragma unroll
  for (int i = 0; i < 4; ++i)
#pragma unroll
    for (int j = 0; j < 4; ++j) {
      const int gcol = bn + wc + j * 16 + ml;
      const float bv_ = bo[gcol];
#pragma unroll
      for (int r = 0; r < 4; ++r) {
        const int grow = bm + wr + i * 16 + quad * 4 + r;
        const size_t idx = (size_t)grow * HID + gcol;
        h[idx] = acc[i][j][r] + bv_ + x[idx];
      }
    }
}

// ---- LayerNorm + 9-label classifier: ONE WAVE per row (R15).
//      shfl_xor-only reductions -> zero barriers, zero LDS. 4 rows/block. ----
__global__ __launch_bounds__(256) void ln_logits_kernel(
    const float* __restrict__ h, const float* __restrict__ g,
    const float* __restrict__ bta, const float* __restrict__ Ws,
    const float* __restrict__ bsv, float* __restrict__ span)
{
  const int row = blockIdx.x * 4 + (threadIdx.x >> 6);
  const int lane = threadIdx.x & 63;
  const float* hr = h + (size_t)row * HID;
  float4 v[3];
#pragma unroll
  for (int sgm = 0; sgm < 3; ++sgm) v[sgm] = ((const float4*)hr)[sgm * 64 + lane];
  float s = 0.f, sq = 0.f;
#pragma unroll
  for (int sgm = 0; sgm < 3; ++sgm) {
    s  += v[sgm].x + v[sgm].y + v[sgm].z + v[sgm].w;
    sq += v[sgm].x * v[sgm].x + v[sgm].y * v[sgm].y
        + v[sgm].z * v[sgm].z + v[sgm].w * v[sgm].w;
  }
#pragma unroll
  for (int o = 1; o < 64; o <<= 1) { s += __shfl_xor(s, o, 64); sq += __shfl_xor(sq, o, 64); }
  const float mu = s / 768.0f;
  const float rs = rsqrtf(sq / 768.0f - mu * mu + 1e-5f);
  float pl[9];
#pragma unroll
  for (int l = 0; l < 9; ++l) pl[l] = 0.f;
#pragma unroll
  for (int sgm = 0; sgm < 3; ++sgm) {
    const int c0 = sgm * 256 + lane * 4;
    const float4 gg = ((const float4*)g)[sgm * 64 + lane];
    const float4 bb = ((const float4*)bta)[sgm * 64 + lane];
    const float n0 = (v[sgm].x - mu) * rs * gg.x + bb.x;
    const float n1 = (v[sgm].y - mu) * rs * gg.y + bb.y;
    const float n2 = (v[sgm].z - mu) * rs * gg.z + bb.z;
    const float n3 = (v[sgm].w - mu) * rs * gg.w + bb.w;
    const float* w0 = Ws + (size_t)c0 * 9;
#pragma unroll
    for (int l = 0; l < 9; ++l)
      pl[l] += n0 * w0[l] + n1 * w0[9 + l] + n2 * w0[18 + l] + n3 * w0[27 + l];
  }
#pragma unroll
  for (int l = 0; l < 9; ++l)
#pragma unroll
    for (int o = 1; o < 64; o <<= 1) pl[l] += __shfl_xor(pl[l], o, 64);
  if (lane == 0) {
    float* sp = span + (size_t)row * 9;
#pragma unroll
    for (int l = 0; l < 9; ++l) sp[l] = pl[l] + bsv[l];
  }
}

// ---- entity-bias bump ----
__global__ __launch_bounds__(256) void bump_kernel(
    const float* __restrict__ span, const float* __restrict__ eb, float* __restrict__ out)
{
  const int idx = blockIdx.x * 256 + threadIdx.x;
  if (idx >= ROWS) return;
  const int j = idx & (SEQ - 1);
  const float* sl = span + (size_t)idx * 9;
  float v[9];
#pragma unroll
  for (int l = 0; l < 9; ++l) v[l] = sl[l];
  if (j >= 1) {
    const float* sp = sl - 9;
    float m = sp[0]; int am = 0;
#pragma unroll
    for (int l = 1; l < 9; ++l) { const float t = sp[l]; if (t > m) { m = t; am = l; } }
    if (am == 1) v[2] += 2.0f * eb[2];
  }
#pragma unroll
  for (int l = 0; l < 9; ++l) out[(size_t)idx * 9 + l] = v[l];
}

extern "C" void kernel_launch(void* const* d_in, const int* in_sizes, int n_in,
                              void* d_out, int out_size, void* d_ws, size_t ws_size,
                              hipStream_t stream)
{
  (void)in_sizes; (void)n_in; (void)out_size; (void)ws_size;
  const float* x   = (const float*)d_in[0];
  const float* Wq  = (const float*)d_in[1];
  const float* bq  = (const float*)d_in[2];
  const float* Wk  = (const float*)d_in[3];
  const float* bk  = (const float*)d_in[4];
  const float* Wv  = (const float*)d_in[5];
  const float* bv  = (const float*)d_in[6];
  const float* Wo  = (const float*)d_in[7];
  const float* bo  = (const float*)d_in[8];
  const float* lng = (const float*)d_in[9];
  const float* lnb = (const float*)d_in[10];
  const float* Ws  = (const float*)d_in[11];
  const float* bs  = (const float*)d_in[12];
  const float* eb  = (const float*)d_in[13];
  float* out = (float*)d_out;

  char* ws = (char*)d_ws;
  u16* xh  = (u16*)(ws + 0);                       // fp16 x (12.6MB)
  u16* WTh = (u16*)(ws + 25165824);                // fp16 WT (4 matrices)
  u16* qh  = (u16*)(ws + 34603008);
  u16* kh  = (u16*)(ws + 59768832);
  u16* vTh = (u16*)(ws + 84934656);                // fp16 vT (12.6MB)
  float* hb = (float*)(ws + 84934656);             // fp32 h (25MB, overwrites vT after attn)
  float* spanb = (float*)(ws + 152043520);
  u16* ctxh = qh;                                  // q dead after attn

  splitx<<<dim3(1572864 / 256), 256, 0, stream>>>(x, xh);
  wsplit<<<dim3(24, 24, 4), 256, 0, stream>>>(Wq, Wk, Wv, Wo, WTh);
  qkv_mm<<<dim3(1152), 256, 0, stream>>>(xh, WTh, bq, bk, bv, qh, kh, vTh);
  attn_fused<<<dim3(512), 256, 0, stream>>>(qh, kh, vTh, ctxh);
  proj_mm<<<dim3(384), 256, 0, stream>>>(ctxh, WTh, bo, x, hb);
  ln_logits_kernel<<<dim3(ROWS / 4), 256, 0, stream>>>(hb, lng, lnb, Ws, bs, spanb);
  bump_kernel<<<dim3(ROWS / 256), 256, 0, stream>>>(spanb, eb, out);
}

// Round 9
// 197.483 us; speedup vs baseline: 1.0898x; 1.0898x over previous
//
#include <hip/hip_runtime.h>
#include <math.h>

#define SEQ 512
#define HID 768
#define NBATCH 16
#define ROWS 8192
#define INV_SQRT_D 0.07216878364870323f

typedef short s8v __attribute__((ext_vector_type(8)));
typedef _Float16 h8v __attribute__((ext_vector_type(8)));
typedef float f4v __attribute__((ext_vector_type(4)));
typedef unsigned short u16;

// ---- fp16 helpers (RNE) ----
__device__ __forceinline__ u16 f2h(float f) {
  _Float16 h = (_Float16)f;
  return __builtin_bit_cast(u16, h);
}
__device__ __forceinline__ float h2f(u16 u) {
  return (float)__builtin_bit_cast(_Float16, u);
}

// ---- async global->LDS 16B copy (m97/m151: 1.35x over reg-staging) ----
// LDS dest must be wave-uniform base (HW adds lane*16); global src is per-lane.
__device__ __forceinline__ void llds16(const u16* g, u16* l) {
  __builtin_amdgcn_global_load_lds(
      (const __attribute__((address_space(1))) void*)g,
      (__attribute__((address_space(3))) void*)l, 16, 0, 0);
}

// ---------------------------------------------------------------------------
// fp16 GEMM core (R16 known-good, reverted after R7/R8 pipelining failures):
// BK=64 via paired 32-wide sub-tiles, staged with global_load_lds. One
// barrier-pair per 64-K step, 32 MFMA per pair; cross-block TLP (4 blocks/CU)
// hides the drain (m114). R7 (2-phase w/ drain) and R8 (counted-vmcnt 2-deep)
// both measured SLOWER (49/44.6 vs ~36 us) -- m131-m140's plateau confirmed.
// Source carries the csw pre-swizzle (m173); reads keep fo2 (conflict-free).
// LDS 32KB: sub0 {A@0,B@4096}, sub1 {A@8192,B@12288} (u16 idx).
// ---------------------------------------------------------------------------
template <int KSTEPS>   // number of 32-wide steps; must be even
__device__ __forceinline__ void mm_core128(
    const u16* __restrict__ A, const int lda,
    const u16* __restrict__ B, const int ldb,
    u16* lds, f4v (&acc)[4][4])
{
  const int tid = threadIdx.x;
  const int w = tid >> 6, ln = tid & 63;
  const u16* src = (w >> 1) ? B : A;
  const int ld = (w >> 1) ? ldb : lda;
  const int half = w & 1;
  const int srow = ln >> 2;
  const int csw  = ((ln & 3) - (ln >> 3)) & 3;
  const int ml = ln & 15;
  const int fo2 = (((ln >> 4) + ((ln >> 1) & 3)) & 3) * 8;
  const int wr = (w >> 1) * 64, wc = (w & 1) * 64;

  const u16* gp[4];
  u16* lp[4];
#pragma unroll
  for (int t = 0; t < 4; ++t) {
    const int row = half * 64 + t * 16 + srow;
    gp[t] = src + (size_t)row * ld + csw * 8;
    lp[t] = lds + (w >> 1) * 4096 + half * 2048 + t * 512;   // wave-uniform
  }

  for (int kp = 0; kp < KSTEPS / 2; ++kp) {
    const int k0 = kp * 64;
    __syncthreads();                       // prev-iter LDS reads done
#pragma unroll
    for (int t = 0; t < 4; ++t) {
      llds16(gp[t] + k0,      lp[t]);
      llds16(gp[t] + k0 + 32, lp[t] + 8192);
    }
    __syncthreads();                       // vmcnt(0) drain + visibility
#pragma unroll
    for (int sub = 0; sub < 2; ++sub) {
      const int so = sub * 8192;
      h8v a[4], b[4];
#pragma unroll
      for (int i = 0; i < 4; ++i)
        a[i] = *(const h8v*)&lds[so + (wr + i * 16 + ml) * 32 + fo2];
#pragma unroll
      for (int j = 0; j < 4; ++j)
        b[j] = *(const h8v*)&lds[so + 4096 + (wc + j * 16 + ml) * 32 + fo2];
#pragma unroll
      for (int i = 0; i < 4; ++i)
#pragma unroll
        for (int j = 0; j < 4; ++j)
          acc[i][j] = __builtin_amdgcn_mfma_f32_16x16x32_f16(a[i], b[j], acc[i][j], 0, 0, 0);
    }
  }
}

// ---- prep: x -> fp16 ----
__global__ __launch_bounds__(256) void splitx(const float* __restrict__ x,
                                              u16* __restrict__ xh)
{
  const int i = blockIdx.x * 256 + threadIdx.x;
  const float4 v = ((const float4*)x)[i];
  ((ushort4*)xh)[i] = make_ushort4(f2h(v.x), f2h(v.y), f2h(v.z), f2h(v.w));
}

// ---- prep: transpose weights: WT[z][n][k] = W_z[k][n], fp16 ----
__global__ __launch_bounds__(256) void wsplit(
    const float* __restrict__ Wq, const float* __restrict__ Wk,
    const float* __restrict__ Wv, const float* __restrict__ Wo,
    u16* __restrict__ WTh)
{
  __shared__ float t[32][33];
  const int z = blockIdx.z;
  const float* W = (z == 0) ? Wq : (z == 1) ? Wk : (z == 2) ? Wv : Wo;
  const int n0 = blockIdx.x * 32, k0 = blockIdx.y * 32;
  const int tx = threadIdx.x & 31, ty = threadIdx.x >> 5;
#pragma unroll
  for (int i = 0; i < 4; ++i)
    t[ty + 8 * i][tx] = W[(size_t)(k0 + ty + 8 * i) * HID + n0 + tx];
  __syncthreads();
#pragma unroll
  for (int i = 0; i < 4; ++i) {
    const float v = t[tx][ty + 8 * i];
    const size_t idx = (size_t)z * HID * HID + (size_t)(n0 + ty + 8 * i) * HID + k0 + tx;
    WTh[idx] = f2h(v);
  }
}

// ---- QKV GEMM, XCD-swizzled 1D grid (1152 blocks), gll fp16 BK=64 core.
//      All epilogues go through LDS for coalesced 16B stores. ----
__global__ __launch_bounds__(256, 4) void qkv_mm(
    const u16* __restrict__ xh, const u16* __restrict__ WTh,
    const float* __restrict__ bq, const float* __restrict__ bk, const float* __restrict__ bv,
    u16* __restrict__ qh, u16* __restrict__ kh, u16* __restrict__ vTh)
{
  __shared__ u16 lds[18432];        // mm_core: 16384; epilogue: 128x144 max
  const int id = blockIdx.x;
  const int xcd = id & 7;
  const int s = id >> 3;            // 0..143
  const int bx = s % 6;
  const int yl = (s / 6) & 7;
  const int z  = s / 48;
  const int bm = (yl * 8 + xcd) * 128;
  const int bn = bx * 128;
  const size_t wtoff = (size_t)z * HID * HID + (size_t)bn * HID;
  f4v acc[4][4];
#pragma unroll
  for (int i = 0; i < 4; ++i)
#pragma unroll
    for (int j = 0; j < 4; ++j) acc[i][j] = (f4v)0.f;
  mm_core128<24>(xh + (size_t)bm * HID, HID, WTh + wtoff, HID, lds, acc);
  const int tid = threadIdx.x, w = tid >> 6, ln = tid & 63;
  const int ml = ln & 15, quad = ln >> 4;
  const int wr = (w >> 1) * 64, wc = (w & 1) * 64;
  if (z == 2) {
    // transpose via LDS: lds[n_local*136 + seq_local], then coalesced out
    __syncthreads();                       // mm_core's last LDS reads done
#pragma unroll
    for (int i = 0; i < 4; ++i)
#pragma unroll
      for (int j = 0; j < 4; ++j) {
        const int ncol = wc + j * 16 + ml;
        const float bv_ = bv[bn + ncol];
#pragma unroll
        for (int r = 0; r < 4; ++r) {
          const int srow = wr + i * 16 + quad * 4 + r;
          lds[ncol * 136 + srow] = f2h(acc[i][j][r] + bv_);
        }
      }
    __syncthreads();
    u16* vb = vTh + (size_t)(bm >> 9) * HID * SEQ;
    const int sq0 = bm & 511;
    const int c8 = (tid & 15) * 8;
#pragma unroll
    for (int p = 0; p < 8; ++p) {
      const int nl = p * 16 + (tid >> 4);  // 0..127
      const s8v val = *(const s8v*)&lds[nl * 136 + c8];
      *(s8v*)&vb[(size_t)(bn + nl) * SEQ + sq0 + c8] = val;
    }
  } else {
    // q/k: row-major LDS tile (stride 132), then 16B coalesced row stores
    const float* bias = (z == 0) ? bq : bk;
    u16* dst = (z == 0) ? qh : kh;
    __syncthreads();                       // mm_core's last LDS reads done
#pragma unroll
    for (int i = 0; i < 4; ++i)
#pragma unroll
      for (int j = 0; j < 4; ++j) {
        const int col = wc + j * 16 + ml;
        const float bv_ = bias[bn + col];
#pragma unroll
        for (int r = 0; r < 4; ++r) {
          const int row = wr + i * 16 + quad * 4 + r;
          lds[row * 132 + col] = f2h(acc[i][j][r] + bv_);
        }
      }
    __syncthreads();
    const int c8 = (tid & 15) * 8;
#pragma unroll
    for (int p = 0; p < 8; ++p) {
      const int rl = p * 16 + (tid >> 4);  // 0..127
      const s8v val = *(const s8v*)&lds[rl * 132 + c8];
      *(s8v*)&dst[(size_t)(bm + rl) * HID + bn + c8] = val;
    }
  }
}

// ---------------------------------------------------------------------------
// FLASH attention v5 (R16): 64 Q-rows/block, 512 blocks = 2 blocks/CU, one
// resident round. K/V staging via global_load_lds direct (m97 schedule):
// K = 6 sub-tiles [64][32], V = 2 sub-tiles [192][32], csw/fo2 swizzle on the
// per-lane GLOBAL source (m173), LDS dest linear-in-lane. QK^T 24 MFMA/wave
// -> max-free exp via g-table (exact; validated R11+) -> P[64][72] -> PV
// 24 MFMA/wave. Grid XCD-bijective: 8 (b,h)/XCD -> K+V 3.1MB < 4MB L2.
// LDS: K@0 (12288), V@12288 (12288), P@24576 (4608) u16 = 57KB +gtab+red.
// ---------------------------------------------------------------------------
__global__ __launch_bounds__(256, 2) void attn_fused(
    const u16* __restrict__ qh, const u16* __restrict__ kh,
    const u16* __restrict__ vTh, u16* __restrict__ ch)
{
  __shared__ u16 lds[29184];
  __shared__ float gtab[1024];
  __shared__ float red[4][32];
  const int f = blockIdx.x;            // 512 blocks
  const int xcd = f & 7, s = f >> 3;   // s: 0..63
  const int z = xcd * 8 + (s >> 3);    // (b,h) 0..63, 8 per XCD
  const int bm = (s & 7) * 64;
  const int b = z >> 2, hh = z & 3;
  const int tid = threadIdx.x, w = tid >> 6, ln = tid & 63;
  const int ml = ln & 15, quad = ln >> 4;
  const int rh = w >> 1, ch2 = w & 1;  // row-half / col-half of the wave
  const int fo2 = ((quad + ((ml >> 1) & 3)) & 3) * 8;

  // g-table: idx = (srow - scol) + 511
  for (int t = tid; t < 1023; t += 256) {
    const float fd = fabsf((float)(t - 511));
    gtab[t] = INV_SQRT_D * __expf(-0.1f * fminf(fd, 5.0f)) - 0.1f * fd;
  }

  const u16* qbase = qh + (size_t)(b * SEQ + bm + rh * 32) * HID + hh * 192;
  const u16* kbase = kh + (size_t)b * SEQ * HID + hh * 192;
  const u16* vbase = vTh + (size_t)b * HID * SEQ + (size_t)(hh * 192) * SEQ;

  // Q fragments in registers (wave's 32 rows)
  h8v qf[2][6];
#pragma unroll
  for (int i = 0; i < 2; ++i)
#pragma unroll
    for (int ks = 0; ks < 6; ++ks)
      qf[i][ks] = *(const h8v*)(qbase + (size_t)(i * 16 + ml) * HID + ks * 32 + quad * 8);

  // gll staging geometry: lane ln covers row (ln>>2), slot (ln&3); the
  // conflict-free swizzle is applied on the SOURCE chunk index (csw).
  const int srow16 = ln >> 2;
  const int csw = ((ln & 3) - (ln >> 3)) & 3;
  const u16* ksrc = kbase + (size_t)(w * 16 + srow16) * HID + csw * 8;
  const u16* vsrc = vbase + (size_t)(w * 48 + srow16) * SEQ + csw * 8;

  f4v acc2[2][6];
#pragma unroll
  for (int i = 0; i < 2; ++i)
#pragma unroll
    for (int jj = 0; jj < 6; ++jj) acc2[i][jj] = (f4v)0.f;
  float rsum[2][4];
#pragma unroll
  for (int i = 0; i < 2; ++i)
#pragma unroll
    for (int r = 0; r < 4; ++r) rsum[i][r] = 0.f;

  for (int j = 0; j < 8; ++j) {
    __syncthreads();                       // b1: prev-iter LDS reads done
    // ---- stage K_j (6 sub-tiles [64][32]) + V_j (2 sub-tiles [192][32]) ----
#pragma unroll
    for (int st = 0; st < 6; ++st)
      llds16(ksrc + (size_t)(j * 64) * HID + st * 32, lds + st * 2048 + w * 512);
#pragma unroll
    for (int st = 0; st < 2; ++st)
#pragma unroll
      for (int o = 0; o < 3; ++o)
        llds16(vsrc + (size_t)(o * 16) * SEQ + j * 64 + st * 32,
               lds + 12288 + st * 6144 + w * 1536 + o * 512);
    __syncthreads();                       // b2: vmcnt(0) drain + visibility
    // ---- QK^T: 24 MFMA/wave (64Q x 32K per wave) ----
    f4v sacc[2][2];
    sacc[0][0] = (f4v)0.f; sacc[0][1] = (f4v)0.f;
    sacc[1][0] = (f4v)0.f; sacc[1][1] = (f4v)0.f;
    __builtin_amdgcn_s_setprio(1);
#pragma unroll
    for (int ks = 0; ks < 6; ++ks) {
      h8v kf0 = *(const h8v*)&lds[ks * 2048 + (ch2 * 32 + ml) * 32 + fo2];
      h8v kf1 = *(const h8v*)&lds[ks * 2048 + (ch2 * 32 + 16 + ml) * 32 + fo2];
      sacc[0][0] = __builtin_amdgcn_mfma_f32_16x16x32_f16(qf[0][ks], kf0, sacc[0][0], 0, 0, 0);
      sacc[1][0] = __builtin_amdgcn_mfma_f32_16x16x32_f16(qf[1][ks], kf0, sacc[1][0], 0, 0, 0);
      sacc[0][1] = __builtin_amdgcn_mfma_f32_16x16x32_f16(qf[0][ks], kf1, sacc[0][1], 0, 0, 0);
      sacc[1][1] = __builtin_amdgcn_mfma_f32_16x16x32_f16(qf[1][ks], kf1, sacc[1][1], 0, 0, 0);
    }
    __builtin_amdgcn_s_setprio(0);
    // ---- transform + P write (max-free exp; 1 exp/elem via g-table) ----
#pragma unroll
    for (int i = 0; i < 2; ++i)
#pragma unroll
      for (int j2 = 0; j2 < 2; ++j2) {
        const int lcol = ch2 * 32 + j2 * 16 + ml;
        const int scolg = j * 64 + lcol;
#pragma unroll
        for (int r = 0; r < 4; ++r) {
          const int lrow = rh * 32 + i * 16 + quad * 4 + r;
          const float g = gtab[bm + lrow - scolg + 511];
          const float p = __expf(fmaf(sacc[i][j2][r], INV_SQRT_D, g));
          rsum[i][r] += p;
          lds[24576 + lrow * 72 + lcol] = f2h(p);
        }
      }
    __syncthreads();                       // b3: P_j visible
    // ---- PV: 24 MFMA/wave (64Q x 96 head-dims per wave) ----
    __builtin_amdgcn_s_setprio(1);
#pragma unroll
    for (int ks = 0; ks < 2; ++ks) {
      h8v pf[2], vf[6];
#pragma unroll
      for (int i = 0; i < 2; ++i)
        pf[i] = *(const h8v*)&lds[24576 + (rh * 32 + i * 16 + ml) * 72 + ks * 32 + quad * 8];
#pragma unroll
      for (int jj = 0; jj < 6; ++jj)
        vf[jj] = *(const h8v*)&lds[12288 + ks * 6144 + (ch2 * 96 + jj * 16 + ml) * 32 + fo2];
#pragma unroll
      for (int i = 0; i < 2; ++i)
#pragma unroll
        for (int jj = 0; jj < 6; ++jj)
          acc2[i][jj] = __builtin_amdgcn_mfma_f32_16x16x32_f16(pf[i], vf[jj], acc2[i][jj], 0, 0, 0);
    }
    __builtin_amdgcn_s_setprio(0);
  }

  // ---- final row-sum reduce ----
#pragma unroll
  for (int i = 0; i < 2; ++i)
#pragma unroll
    for (int r = 0; r < 4; ++r) {
      float t = rsum[i][r];
#pragma unroll
      for (int o = 1; o < 16; o <<= 1) t += __shfl_xor(t, o, 64);
      rsum[i][r] = t;
    }
  if (ml == 0) {
#pragma unroll
    for (int i = 0; i < 2; ++i)
#pragma unroll
      for (int r = 0; r < 4; ++r) red[w][i * 16 + quad * 4 + r] = rsum[i][r];
  }
  __syncthreads();

  // ---- ctx out (normalize here) ----
#pragma unroll
  for (int i = 0; i < 2; ++i)
#pragma unroll
    for (int r = 0; r < 4; ++r) {
      const int lr = i * 16 + quad * 4 + r;
      const float is = 1.0f / (red[rh * 2][lr] + red[rh * 2 + 1][lr]);
      const int m = bm + rh * 32 + lr;
#pragma unroll
      for (int jj = 0; jj < 6; ++jj) {
        const int gcol = hh * 192 + ch2 * 96 + jj * 16 + ml;
        ch[(size_t)(b * SEQ + m) * HID + gcol] = f2h(acc2[i][jj][r] * is);
      }
    }
}

// ---- projection GEMM + bias + residual -> h FP16 (R19): epilogue through
//      LDS (coalesced 16B stores), residual from fp16 xh; saves ~37MB HBM. ----
__global__ __launch_bounds__(256, 4) void proj_mm(
    const u16* __restrict__ ch, const u16* __restrict__ WTh,
    const float* __restrict__ bo, const u16* __restrict__ xh, u16* __restrict__ hh)
{
  __shared__ u16 lds[18432];
  const int id = blockIdx.x;
  const int xcd = id & 7;
  const int s = id >> 3;            // 0..47
  const int bx = s % 6;
  const int yl = s / 6;             // 0..7
  const int bm = (yl * 8 + xcd) * 128;
  const int bn = bx * 128;
  const size_t wtoff = (size_t)3 * HID * HID + (size_t)bn * HID;
  f4v acc[4][4];
#pragma unroll
  for (int i = 0; i < 4; ++i)
#pragma unroll
    for (int j = 0; j < 4; ++j) acc[i][j] = (f4v)0.f;
  mm_core128<24>(ch + (size_t)bm * HID, HID, WTh + wtoff, HID, lds, acc);
  const int tid = threadIdx.x, w = tid >> 6, ln = tid & 63;
  const int ml = ln & 15, quad = ln >> 4;
  const int wr = (w >> 1) * 64, wc = (w & 1) * 64;
  __syncthreads();                       // mm_core's last LDS reads done
#pragma unroll
  for (int i = 0; i < 4; ++i)
#pragma unroll
    for (int j = 0; j < 4; ++j) {
      const int col = wc + j * 16 + ml;
      const float bv_ = bo[bn + col];
#pragma unroll
      for (int r = 0; r < 4; ++r) {
        const int row = wr + i * 16 + quad * 4 + r;
        lds[row * 132 + col] = f2h(acc[i][j][r] + bv_);
      }
    }
  __syncthreads();
  const int c8 = (tid & 15) * 8;
#pragma unroll
  for (int p = 0; p < 8; ++p) {
    const int rl = p * 16 + (tid >> 4);  // 0..127
    const size_t goff = (size_t)(bm + rl) * HID + bn + c8;
    const h8v ov = __builtin_bit_cast(h8v, *(const s8v*)&lds[rl * 132 + c8]);
    const h8v xv = __builtin_bit_cast(h8v, *(const s8v*)&xh[goff]);
    const h8v sum = ov + xv;             // h = proj_out + x (fp16)
    *(s8v*)&hh[goff] = __builtin_bit_cast(s8v, sum);
  }
}

// ---- LayerNorm + 9-label classifier: ONE WAVE per row, fp16 h input (R19).
//      shfl_xor-only reductions -> zero barriers, zero LDS. 4 rows/block. ----
__global__ __launch_bounds__(256) void ln_logits_kernel(
    const u16* __restrict__ hh, const float* __restrict__ g,
    const float* __restrict__ bta, const float* __restrict__ Ws,
    const float* __restrict__ bsv, float* __restrict__ span)
{
  const int row = blockIdx.x * 4 + (threadIdx.x >> 6);
  const int lane = threadIdx.x & 63;
  const u16* hr = hh + (size_t)row * HID;
  float v[3][4];
#pragma unroll
  for (int sgm = 0; sgm < 3; ++sgm) {
    const ushort4 raw = *(const ushort4*)&hr[sgm * 256 + lane * 4];
    v[sgm][0] = h2f(raw.x); v[sgm][1] = h2f(raw.y);
    v[sgm][2] = h2f(raw.z); v[sgm][3] = h2f(raw.w);
  }
  float s = 0.f, sq = 0.f;
#pragma unroll
  for (int sgm = 0; sgm < 3; ++sgm)
#pragma unroll
    for (int e = 0; e < 4; ++e) { s += v[sgm][e]; sq += v[sgm][e] * v[sgm][e]; }
#pragma unroll
  for (int o = 1; o < 64; o <<= 1) { s += __shfl_xor(s, o, 64); sq += __shfl_xor(sq, o, 64); }
  const float mu = s / 768.0f;
  const float rs = rsqrtf(sq / 768.0f - mu * mu + 1e-5f);
  float pl[9];
#pragma unroll
  for (int l = 0; l < 9; ++l) pl[l] = 0.f;
#pragma unroll
  for (int sgm = 0; sgm < 3; ++sgm) {
    const int c0 = sgm * 256 + lane * 4;
    const float4 gg = ((const float4*)g)[sgm * 64 + lane];
    const float4 bb = ((const float4*)bta)[sgm * 64 + lane];
    const float n0 = (v[sgm][0] - mu) * rs * gg.x + bb.x;
    const float n1 = (v[sgm][1] - mu) * rs * gg.y + bb.y;
    const float n2 = (v[sgm][2] - mu) * rs * gg.z + bb.z;
    const float n3 = (v[sgm][3] - mu) * rs * gg.w + bb.w;
    const float* w0 = Ws + (size_t)c0 * 9;
#pragma unroll
    for (int l = 0; l < 9; ++l)
      pl[l] += n0 * w0[l] + n1 * w0[9 + l] + n2 * w0[18 + l] + n3 * w0[27 + l];
  }
#pragma unroll
  for (int l = 0; l < 9; ++l)
#pragma unroll
    for (int o = 1; o < 64; o <<= 1) pl[l] += __shfl_xor(pl[l], o, 64);
  if (lane == 0) {
    float* sp = span + (size_t)row * 9;
#pragma unroll
    for (int l = 0; l < 9; ++l) sp[l] = pl[l] + bsv[l];
  }
}

// ---- entity-bias bump ----
__global__ __launch_bounds__(256) void bump_kernel(
    const float* __restrict__ span, const float* __restrict__ eb, float* __restrict__ out)
{
  const int idx = blockIdx.x * 256 + threadIdx.x;
  if (idx >= ROWS) return;
  const int j = idx & (SEQ - 1);
  const float* sl = span + (size_t)idx * 9;
  float v[9];
#pragma unroll
  for (int l = 0; l < 9; ++l) v[l] = sl[l];
  if (j >= 1) {
    const float* sp = sl - 9;
    float m = sp[0]; int am = 0;
#pragma unroll
    for (int l = 1; l < 9; ++l) { const float t = sp[l]; if (t > m) { m = t; am = l; } }
    if (am == 1) v[2] += 2.0f * eb[2];
  }
#pragma unroll
  for (int l = 0; l < 9; ++l) out[(size_t)idx * 9 + l] = v[l];
}

extern "C" void kernel_launch(void* const* d_in, const int* in_sizes, int n_in,
                              void* d_out, int out_size, void* d_ws, size_t ws_size,
                              hipStream_t stream)
{
  (void)in_sizes; (void)n_in; (void)out_size; (void)ws_size;
  const float* x   = (const float*)d_in[0];
  const float* Wq  = (const float*)d_in[1];
  const float* bq  = (const float*)d_in[2];
  const float* Wk  = (const float*)d_in[3];
  const float* bk  = (const float*)d_in[4];
  const float* Wv  = (const float*)d_in[5];
  const float* bv  = (const float*)d_in[6];
  const float* Wo  = (const float*)d_in[7];
  const float* bo  = (const float*)d_in[8];
  const float* lng = (const float*)d_in[9];
  const float* lnb = (const float*)d_in[10];
  const float* Ws  = (const float*)d_in[11];
  const float* bs  = (const float*)d_in[12];
  const float* eb  = (const float*)d_in[13];
  float* out = (float*)d_out;

  char* ws = (char*)d_ws;
  u16* xh  = (u16*)(ws + 0);                       // fp16 x (12.6MB)
  u16* WTh = (u16*)(ws + 25165824);                // fp16 WT (4 matrices)
  u16* qh  = (u16*)(ws + 34603008);
  u16* kh  = (u16*)(ws + 59768832);
  u16* vTh = (u16*)(ws + 84934656);                // fp16 vT (12.6MB)
  u16* hh  = (u16*)(ws + 110100480);               // fp16 h (12.6MB)
  float* spanb = (float*)(ws + 152043520);
  u16* ctxh = qh;                                  // q dead after attn

  splitx<<<dim3(1572864 / 256), 256, 0, stream>>>(x, xh);
  wsplit<<<dim3(24, 24, 4), 256, 0, stream>>>(Wq, Wk, Wv, Wo, WTh);
  qkv_mm<<<dim3(1152), 256, 0, stream>>>(xh, WTh, bq, bk, bv, qh, kh, vTh);
  attn_fused<<<dim3(512), 256, 0, stream>>>(qh, kh, vTh, ctxh);
  proj_mm<<<dim3(384), 256, 0, stream>>>(ctxh, WTh, bo, xh, hh);
  ln_logits_kernel<<<dim3(ROWS / 4), 256, 0, stream>>>(hh, lng, lnb, Ws, bs, spanb);
  bump_kernel<<<dim3(ROWS / 256), 256, 0, stream>>>(spanb, eb, out);
}